// Round 1
// baseline (806.052 us; speedup 1.0000x reference)
//
#include <hip/hip_runtime.h>

// ---- problem constants (from reference) ----
#define NB 2
#define NT 3
#define NCAM 6
#define NC 16
#define FD 48
#define FH 24
#define FW 64
#define GX 100
#define GY 100
#define GZ 8
#define OC 40
#define NVOX (GX * GY * GZ)          // 80000
#define FSZ (FD * FH * FW)           // 73728 floats per channel volume
#define CAMSZ (NC * FSZ)             // per-camera feature volume
#define BTSZ (NCAM * CAMSZ)          // per-(b,t) feature block
#define HSZ ((size_t)NB * NT * OC * NVOX)  // 19,200,000 floats

// ----------------------------------------------------------------------------
// Setup: P[b,t,n] = intrins[b] @ RT[b,t,n][:3,:]  (3x4)
//        theta[b,t] = cumulative affine (3x4): t=2 -> I, t=1 -> M4[b,1],
//                     t=0 -> M4[b,0] @ M4[b,1]   (M4 = [DoF[:3,:]; 0 0 0 1])
// ----------------------------------------------------------------------------
__global__ void setup_kernel(const float* __restrict__ RT,
                             const float* __restrict__ intrins,
                             const float* __restrict__ DoF,
                             float* __restrict__ P,
                             float* __restrict__ theta) {
    int tid = threadIdx.x;
    if (tid < NB * NT * NCAM) {
        int n = tid % NCAM;
        int bt = tid / NCAM;
        int b = bt / NT;
        const float* I3 = intrins + b * 9;
        const float* R = RT + (size_t)tid * 16;
        float* Pp = P + tid * 12;
        for (int r = 0; r < 3; ++r)
            for (int c = 0; c < 4; ++c) {
                float s = 0.f;
                for (int k = 0; k < 3; ++k) s += I3[r * 3 + k] * R[k * 4 + c];
                Pp[r * 4 + c] = s;
            }
        (void)n;
    }
    if (tid >= 64 && tid < 64 + NB) {
        int b = tid - 64;
        const float* D0 = DoF + (size_t)(b * NT + 0) * 16;
        const float* D1 = DoF + (size_t)(b * NT + 1) * 16;
        float* th = theta + (size_t)b * NT * 12;
        // t = 2: identity
        for (int i = 0; i < 12; ++i) th[2 * 12 + i] = 0.f;
        th[2 * 12 + 0] = 1.f; th[2 * 12 + 5] = 1.f; th[2 * 12 + 10] = 1.f;
        // t = 1: DoF[b,1][:3,:]
        for (int i = 0; i < 12; ++i) th[1 * 12 + i] = D1[i];
        // t = 0: (M4[b,0] @ M4[b,1])[:3,:]
        for (int r = 0; r < 3; ++r)
            for (int c = 0; c < 4; ++c) {
                float s = (c == 3) ? D0[r * 4 + 3] : 0.f;
                for (int k = 0; k < 3; ++k) s += D0[r * 4 + k] * D1[k * 4 + c];
                th[0 * 12 + r * 4 + c] = s;
            }
    }
}

// ----------------------------------------------------------------------------
// Kernel 1: frustum trilinear sample (6 cams x 16 ch) + W_N matvec + ReLU -> h
// h layout: [b][t][o][gx][gz][gy]   (matches reference transpose(0,1,2,3,4,6,5))
// one thread per (b,t,voxel); 480000 threads = 1875 * 256 exactly
// ----------------------------------------------------------------------------
__global__ __launch_bounds__(256) void sample_mlp1(
    const float* __restrict__ feat,
    const float* __restrict__ P,
    const float* __restrict__ W_N,
    const float* __restrict__ b_N,
    float* __restrict__ h) {
    int tid = blockIdx.x * 256 + threadIdx.x;
    int vid = tid % NVOX;
    int bt = tid / NVOX;
    int gy = vid % GY;
    int r2 = vid / GY;
    int gz = r2 % GZ;
    int gx = r2 / GZ;
    // voxel centers: vs = 1 on all axes
    float X = (float)gx - 49.5f;
    float Y = (float)gy - 49.5f;
    float Z = (float)gz - 2.5f;

    float acc[OC];
#pragma unroll
    for (int o = 0; o < OC; ++o) acc[o] = b_N[o];

    const float* fbt = feat + (size_t)bt * BTSZ;
    for (int n = 0; n < NCAM; ++n) {
        const float* Pp = P + (bt * NCAM + n) * 12;
        float px = Pp[0] * X + Pp[1] * Y + Pp[2] * Z + Pp[3];
        float py = Pp[4] * X + Pp[5] * Y + Pp[6] * Z + Pp[7];
        float pz = Pp[8] * X + Pp[9] * Y + Pp[10] * Z + Pp[11];
        float zc = fmaxf(pz, 1e-5f);
        // ix = u, iy = v, iz = dbin (normalization round-trips exactly)
        float ix = px / zc;
        float iy = py / zc;
        float iz = (pz - 2.0f) * (48.0f / 44.8f);
        float x0 = floorf(ix), y0 = floorf(iy), z0 = floorf(iz);
        float wx1 = ix - x0, wy1 = iy - y0, wz1 = iz - z0;
        float wx0 = 1.f - wx1, wy0 = 1.f - wy1, wz0 = 1.f - wz1;

        float w8[8];
        int off8[8];
#pragma unroll
        for (int k = 0; k < 8; ++k) {
            float xf = x0 + (float)(k & 1);
            float yf = y0 + (float)((k >> 1) & 1);
            float zf = z0 + (float)(k >> 2);
            bool valid = (xf >= 0.f) & (xf <= (float)(FW - 1)) &
                         (yf >= 0.f) & (yf <= (float)(FH - 1)) &
                         (zf >= 0.f) & (zf <= (float)(FD - 1));
            int xi = (int)fminf(fmaxf(xf, 0.f), (float)(FW - 1));
            int yi = (int)fminf(fmaxf(yf, 0.f), (float)(FH - 1));
            int zi = (int)fminf(fmaxf(zf, 0.f), (float)(FD - 1));
            float w = ((k & 1) ? wx1 : wx0) * (((k >> 1) & 1) ? wy1 : wy0) *
                      ((k >> 2) ? wz1 : wz0);
            w8[k] = valid ? w : 0.f;
            off8[k] = (zi * FH + yi) * FW + xi;
        }

        float s[NC];
        const float* fn = fbt + n * CAMSZ;
#pragma unroll
        for (int c = 0; c < NC; ++c) {
            const float* fc = fn + c * FSZ;
            float v = 0.f;
#pragma unroll
            for (int k = 0; k < 8; ++k) v = fmaf(w8[k], fc[off8[k]], v);
            s[c] = v;
        }

        // acc[o] += W_N[o, n*16 + c] * s[c]; uniform-address float4 loads
#pragma unroll
        for (int o = 0; o < OC; ++o) {
            const float4* w4 =
                reinterpret_cast<const float4*>(W_N + o * (NCAM * NC) + n * NC);
#pragma unroll
            for (int q = 0; q < 4; ++q) {
                float4 w = w4[q];
                acc[o] = fmaf(w.x, s[4 * q + 0], acc[o]);
                acc[o] = fmaf(w.y, s[4 * q + 1], acc[o]);
                acc[o] = fmaf(w.z, s[4 * q + 2], acc[o]);
                acc[o] = fmaf(w.w, s[4 * q + 3], acc[o]);
            }
        }
    }

    float* hp = h + (size_t)bt * OC * NVOX + vid;
#pragma unroll
    for (int o = 0; o < OC; ++o) hp[(size_t)o * NVOX] = fmaxf(acc[o], 0.f);
}

// ----------------------------------------------------------------------------
// Kernel 2: temporal affine warp (trilinear on h) + W_T matvec + ReLU -> out
// out layout: [b][o][d][h][w] = (B,40,100,8,100)
// one thread per (b,voxel); 160000 threads = 625 * 256 exactly
// ----------------------------------------------------------------------------
__global__ __launch_bounds__(256) void warp_mlp2(
    const float* __restrict__ h,
    const float* __restrict__ theta,
    const float* __restrict__ W_T,
    const float* __restrict__ b_T,
    float* __restrict__ out) {
    int tid = blockIdx.x * 256 + threadIdx.x;
    int vid = tid % NVOX;
    int b = tid / NVOX;
    int w_ = vid % GY;        // Wp = 100
    int r2 = vid / GY;
    int h_ = r2 % GZ;         // Hp = 8
    int d_ = r2 / GZ;         // Dp = 100

    float xg = -1.f + 2.f * (float)w_ / 99.f;
    float yg = -1.f + 2.f * (float)h_ / 7.f;
    float zg = -1.f + 2.f * (float)d_ / 99.f;

    float acc[OC];
#pragma unroll
    for (int o = 0; o < OC; ++o) acc[o] = b_T[o];

    for (int t = 0; t < NT; ++t) {
        const float* th = theta + (b * NT + t) * 12;
        float g0 = th[0] * xg + th[1] * yg + th[2] * zg + th[3];
        float g1 = th[4] * xg + th[5] * yg + th[6] * zg + th[7];
        float g2 = th[8] * xg + th[9] * yg + th[10] * zg + th[11];
        float ix = (g0 + 1.f) * 0.5f * 99.f;   // W = 100
        float iy = (g1 + 1.f) * 0.5f * 7.f;    // H = 8
        float iz = (g2 + 1.f) * 0.5f * 99.f;   // D = 100
        float x0 = floorf(ix), y0 = floorf(iy), z0 = floorf(iz);
        float wx1 = ix - x0, wy1 = iy - y0, wz1 = iz - z0;
        float wx0 = 1.f - wx1, wy0 = 1.f - wy1, wz0 = 1.f - wz1;

        float w8[8];
        int off8[8];
#pragma unroll
        for (int k = 0; k < 8; ++k) {
            float xf = x0 + (float)(k & 1);
            float yf = y0 + (float)((k >> 1) & 1);
            float zf = z0 + (float)(k >> 2);
            bool valid = (xf >= 0.f) & (xf <= 99.f) &
                         (yf >= 0.f) & (yf <= 7.f) &
                         (zf >= 0.f) & (zf <= 99.f);
            int xi = (int)fminf(fmaxf(xf, 0.f), 99.f);
            int yi = (int)fminf(fmaxf(yf, 0.f), 7.f);
            int zi = (int)fminf(fmaxf(zf, 0.f), 99.f);
            float w = ((k & 1) ? wx1 : wx0) * (((k >> 1) & 1) ? wy1 : wy0) *
                      ((k >> 2) ? wz1 : wz0);
            w8[k] = valid ? w : 0.f;
            off8[k] = (zi * GZ + yi) * GY + xi;   // (D,H,W) strides: 800,100,1
        }

        const float* hb = h + (size_t)(b * NT + t) * OC * NVOX;
        float sval[OC];
#pragma unroll
        for (int o2 = 0; o2 < OC; ++o2) {
            const float* hc = hb + (size_t)o2 * NVOX;
            float v = 0.f;
#pragma unroll
            for (int k = 0; k < 8; ++k) v = fmaf(w8[k], hc[off8[k]], v);
            sval[o2] = v;
        }

        // acc[o] += W_T[o, t*40 + o2] * sval[o2]
#pragma unroll
        for (int o = 0; o < OC; ++o) {
            const float4* w4 =
                reinterpret_cast<const float4*>(W_T + o * (NT * OC) + t * OC);
#pragma unroll
            for (int q = 0; q < 10; ++q) {
                float4 w = w4[q];
                acc[o] = fmaf(w.x, sval[4 * q + 0], acc[o]);
                acc[o] = fmaf(w.y, sval[4 * q + 1], acc[o]);
                acc[o] = fmaf(w.z, sval[4 * q + 2], acc[o]);
                acc[o] = fmaf(w.w, sval[4 * q + 3], acc[o]);
            }
        }
    }

    float* op = out + (size_t)b * OC * NVOX + vid;
#pragma unroll
    for (int o = 0; o < OC; ++o) op[(size_t)o * NVOX] = fmaxf(acc[o], 0.f);
}

extern "C" void kernel_launch(void* const* d_in, const int* in_sizes, int n_in,
                              void* d_out, int out_size, void* d_ws, size_t ws_size,
                              hipStream_t stream) {
    const float* frustum = (const float*)d_in[0];  // (B,T,N,C,FD,FH,FW)
    const float* RT      = (const float*)d_in[1];  // (B,T,N,4,4)
    const float* intrins = (const float*)d_in[2];  // (B,3,3)
    const float* DoF     = (const float*)d_in[3];  // (B,T,4,4)
    const float* W_N     = (const float*)d_in[4];  // (40,96)
    const float* b_N     = (const float*)d_in[5];  // (40)
    const float* W_T     = (const float*)d_in[6];  // (40,120)
    const float* b_T     = (const float*)d_in[7];  // (40)
    float* out = (float*)d_out;

    float* ws = (float*)d_ws;
    float* h_buf = ws;                       // HSZ floats
    float* P_buf = ws + HSZ;                 // 36*12 floats
    float* th_buf = P_buf + NB * NT * NCAM * 12;  // 6*12 floats

    setup_kernel<<<1, 128, 0, stream>>>(RT, intrins, DoF, P_buf, th_buf);

    int n1_blocks = (NB * NT * NVOX) / 256;  // 1875 exactly
    sample_mlp1<<<n1_blocks, 256, 0, stream>>>(frustum, P_buf, W_N, b_N, h_buf);

    int n2_blocks = (NB * NVOX) / 256;       // 625 exactly
    warp_mlp2<<<n2_blocks, 256, 0, stream>>>(h_buf, th_buf, W_T, b_T, out);
}

// Round 2
// 522.402 us; speedup vs baseline: 1.5430x; 1.5430x over previous
//
#include <hip/hip_runtime.h>
#include <hip/hip_bf16.h>

// ---- problem constants (from reference) ----
#define NB 2
#define NT 3
#define NCAM 6
#define NC 16
#define FD 48
#define FH 24
#define FW 64
#define GX 100
#define GY 100
#define GZ 8
#define OC 40
#define NVOX (GX * GY * GZ)          // 80000
#define FSZ (FD * FH * FW)           // 73728 voxels per channel volume
#define CAMSZ (NC * FSZ)             // per-camera feature volume (orig layout)
#define BTSZ (NCAM * CAMSZ)          // per-(b,t) feature block (orig layout)
#define HSZ ((size_t)NB * NT * OC * NVOX)      // 19,200,000 floats
#define FT_ELEMS ((size_t)NB * NT * NCAM * FSZ * NC)  // 42,467,328

static __device__ __forceinline__ unsigned short f2bf_rne(float x) {
    unsigned int u = __float_as_uint(x);
    unsigned int r = (u + 0x7fffu + ((u >> 16) & 1u)) >> 16;
    return (unsigned short)r;
}

// ----------------------------------------------------------------------------
// Setup: P[b,t,n] = intrins[b] @ RT[b,t,n][:3,:]  (3x4)
//        theta[b,t] cumulative affine (3x4): t=2 -> I, t=1 -> M4[b,1],
//        t=0 -> M4[b,0] @ M4[b,1]
// ----------------------------------------------------------------------------
__global__ void setup_kernel(const float* __restrict__ RT,
                             const float* __restrict__ intrins,
                             const float* __restrict__ DoF,
                             float* __restrict__ P,
                             float* __restrict__ theta) {
    int tid = threadIdx.x;
    if (tid < NB * NT * NCAM) {
        int bt = tid / NCAM;
        int b = bt / NT;
        const float* I3 = intrins + b * 9;
        const float* R = RT + (size_t)tid * 16;
        float* Pp = P + tid * 12;
        for (int r = 0; r < 3; ++r)
            for (int c = 0; c < 4; ++c) {
                float s = 0.f;
                for (int k = 0; k < 3; ++k) s += I3[r * 3 + k] * R[k * 4 + c];
                Pp[r * 4 + c] = s;
            }
    }
    if (tid >= 64 && tid < 64 + NB) {
        int b = tid - 64;
        const float* D0 = DoF + (size_t)(b * NT + 0) * 16;
        const float* D1 = DoF + (size_t)(b * NT + 1) * 16;
        float* th = theta + (size_t)b * NT * 12;
        for (int i = 0; i < 12; ++i) th[2 * 12 + i] = 0.f;
        th[2 * 12 + 0] = 1.f; th[2 * 12 + 5] = 1.f; th[2 * 12 + 10] = 1.f;
        for (int i = 0; i < 12; ++i) th[1 * 12 + i] = D1[i];
        for (int r = 0; r < 3; ++r)
            for (int c = 0; c < 4; ++c) {
                float s = (c == 3) ? D0[r * 4 + 3] : 0.f;
                for (int k = 0; k < 3; ++k) s += D0[r * 4 + k] * D1[k * 4 + c];
                th[0 * 12 + r * 4 + c] = s;
            }
    }
}

// ----------------------------------------------------------------------------
// Transpose features (B,T,N,C,FD,FH,FW) -> [btn][pos][C16]  (channel-last)
// reads coalesced per channel, writes 64B (fp32) / 32B (bf16) per thread
// grid: 36*FSZ / 256 = 10368 blocks
// ----------------------------------------------------------------------------
template <typename FT>
__global__ __launch_bounds__(256) void transpose_feat(
    const float* __restrict__ feat, FT* __restrict__ ft) {
    size_t tid = (size_t)blockIdx.x * 256 + threadIdx.x;
    int pos = (int)(tid % FSZ);
    int btn = (int)(tid / FSZ);
    const float* src = feat + (size_t)btn * CAMSZ + pos;
    float v[NC];
#pragma unroll
    for (int c = 0; c < NC; ++c) v[c] = src[(size_t)c * FSZ];
    if constexpr (sizeof(FT) == 4) {
        float4* dst = reinterpret_cast<float4*>(
            (float*)ft + ((size_t)btn * FSZ + pos) * NC);
#pragma unroll
        for (int q = 0; q < 4; ++q)
            dst[q] = make_float4(v[4 * q], v[4 * q + 1], v[4 * q + 2], v[4 * q + 3]);
    } else {
        unsigned int packed[8];
#pragma unroll
        for (int j = 0; j < 8; ++j)
            packed[j] = (unsigned int)f2bf_rne(v[2 * j]) |
                        ((unsigned int)f2bf_rne(v[2 * j + 1]) << 16);
        uint4* dst = reinterpret_cast<uint4*>(
            (unsigned short*)ft + ((size_t)btn * FSZ + pos) * NC);
        dst[0] = make_uint4(packed[0], packed[1], packed[2], packed[3]);
        dst[1] = make_uint4(packed[4], packed[5], packed[6], packed[7]);
    }
}

// ----------------------------------------------------------------------------
// Kernel 1: frustum trilinear sample (6 cams x 16 ch) + W_N matvec + ReLU -> h
// h layout: CHANNEL-LAST [bt][vid][OC]  (vid = gx*GZ*GY + gz*GY + gy, matching
// the reference's (gx, gz, gy) spatial order after its transpose)
// one thread per (b,t,voxel); 480000 threads = 1875 * 256
// ----------------------------------------------------------------------------
template <typename FT, bool CHLAST>
__global__ __launch_bounds__(256) void sample_mlp1(
    const float* __restrict__ feat,   // original layout (used when !CHLAST)
    const FT* __restrict__ ft,        // channel-last (used when CHLAST)
    const float* __restrict__ P,
    const float* __restrict__ W_N,
    const float* __restrict__ b_N,
    float* __restrict__ h) {
    int tid = blockIdx.x * 256 + threadIdx.x;
    int vid = tid % NVOX;
    int bt = tid / NVOX;
    int gy = vid % GY;
    int r2 = vid / GY;
    int gz = r2 % GZ;
    int gx = r2 / GZ;
    float X = (float)gx - 49.5f;
    float Y = (float)gy - 49.5f;
    float Z = (float)gz - 2.5f;

    float acc[OC];
#pragma unroll
    for (int o = 0; o < OC; ++o) acc[o] = b_N[o];

    for (int n = 0; n < NCAM; ++n) {
        const float* Pp = P + (bt * NCAM + n) * 12;
        float px = Pp[0] * X + Pp[1] * Y + Pp[2] * Z + Pp[3];
        float py = Pp[4] * X + Pp[5] * Y + Pp[6] * Z + Pp[7];
        float pz = Pp[8] * X + Pp[9] * Y + Pp[10] * Z + Pp[11];
        float zc = fmaxf(pz, 1e-5f);
        float ix = px / zc;                       // = u (normalization round-trips)
        float iy = py / zc;
        float iz = (pz - 2.0f) * (48.0f / 44.8f); // = dbin
        float x0 = floorf(ix), y0 = floorf(iy), z0 = floorf(iz);
        float wx1 = ix - x0, wy1 = iy - y0, wz1 = iz - z0;
        float wx0 = 1.f - wx1, wy0 = 1.f - wy1, wz0 = 1.f - wz1;

        float w8[8];
        int off8[8];
#pragma unroll
        for (int k = 0; k < 8; ++k) {
            float xf = x0 + (float)(k & 1);
            float yf = y0 + (float)((k >> 1) & 1);
            float zf = z0 + (float)(k >> 2);
            bool valid = (xf >= 0.f) & (xf <= (float)(FW - 1)) &
                         (yf >= 0.f) & (yf <= (float)(FH - 1)) &
                         (zf >= 0.f) & (zf <= (float)(FD - 1));
            int xi = (int)fminf(fmaxf(xf, 0.f), (float)(FW - 1));
            int yi = (int)fminf(fmaxf(yf, 0.f), (float)(FH - 1));
            int zi = (int)fminf(fmaxf(zf, 0.f), (float)(FD - 1));
            float w = ((k & 1) ? wx1 : wx0) * (((k >> 1) & 1) ? wy1 : wy0) *
                      ((k >> 2) ? wz1 : wz0);
            w8[k] = valid ? w : 0.f;
            off8[k] = (zi * FH + yi) * FW + xi;
        }

        float s[NC];
#pragma unroll
        for (int c = 0; c < NC; ++c) s[c] = 0.f;

        if constexpr (CHLAST) {
            const size_t camBase = (size_t)(bt * NCAM + n) * FSZ;
#pragma unroll
            for (int k = 0; k < 8; ++k) {
                float w = w8[k];
                if constexpr (sizeof(FT) == 4) {
                    const float4* cp = reinterpret_cast<const float4*>(
                        (const float*)ft + (camBase + (size_t)off8[k]) * NC);
#pragma unroll
                    for (int q = 0; q < 4; ++q) {
                        float4 v = cp[q];
                        s[4 * q + 0] = fmaf(w, v.x, s[4 * q + 0]);
                        s[4 * q + 1] = fmaf(w, v.y, s[4 * q + 1]);
                        s[4 * q + 2] = fmaf(w, v.z, s[4 * q + 2]);
                        s[4 * q + 3] = fmaf(w, v.w, s[4 * q + 3]);
                    }
                } else {
                    const uint4* cp = reinterpret_cast<const uint4*>(
                        (const unsigned short*)ft + (camBase + (size_t)off8[k]) * NC);
                    uint4 a = cp[0], b2 = cp[1];
                    unsigned int uu[8] = {a.x, a.y, a.z, a.w, b2.x, b2.y, b2.z, b2.w};
#pragma unroll
                    for (int j = 0; j < 8; ++j) {
                        s[2 * j + 0] = fmaf(w, __uint_as_float(uu[j] << 16), s[2 * j + 0]);
                        s[2 * j + 1] = fmaf(w, __uint_as_float(uu[j] & 0xffff0000u), s[2 * j + 1]);
                    }
                }
            }
        } else {
            const float* fn = feat + (size_t)bt * BTSZ + (size_t)n * CAMSZ;
#pragma unroll
            for (int c = 0; c < NC; ++c) {
                const float* fc = fn + (size_t)c * FSZ;
                float v = 0.f;
#pragma unroll
                for (int k = 0; k < 8; ++k) v = fmaf(w8[k], fc[off8[k]], v);
                s[c] = v;
            }
        }

        // acc[o] += W_N[o, n*16 + c] * s[c]
#pragma unroll
        for (int o = 0; o < OC; ++o) {
            const float4* w4 =
                reinterpret_cast<const float4*>(W_N + o * (NCAM * NC) + n * NC);
#pragma unroll
            for (int q = 0; q < 4; ++q) {
                float4 w = w4[q];
                acc[o] = fmaf(w.x, s[4 * q + 0], acc[o]);
                acc[o] = fmaf(w.y, s[4 * q + 1], acc[o]);
                acc[o] = fmaf(w.z, s[4 * q + 2], acc[o]);
                acc[o] = fmaf(w.w, s[4 * q + 3], acc[o]);
            }
        }
    }

    // channel-last store: h[bt][vid][OC]
    float4* hp = reinterpret_cast<float4*>(
        h + ((size_t)bt * NVOX + (size_t)vid) * OC);
#pragma unroll
    for (int q = 0; q < 10; ++q)
        hp[q] = make_float4(fmaxf(acc[4 * q + 0], 0.f), fmaxf(acc[4 * q + 1], 0.f),
                            fmaxf(acc[4 * q + 2], 0.f), fmaxf(acc[4 * q + 3], 0.f));
}

// ----------------------------------------------------------------------------
// Kernel 2: temporal affine warp (trilinear on channel-last h) + W_T + ReLU
// out layout: [b][o][d][h][w] = (B,40,100,8,100)
// one thread per (b,voxel); 160000 threads = 625 * 256
// ----------------------------------------------------------------------------
__global__ __launch_bounds__(256) void warp_mlp2(
    const float* __restrict__ h,
    const float* __restrict__ theta,
    const float* __restrict__ W_T,
    const float* __restrict__ b_T,
    float* __restrict__ out) {
    int tid = blockIdx.x * 256 + threadIdx.x;
    int vid = tid % NVOX;
    int b = tid / NVOX;
    int w_ = vid % GY;        // Wp = 100
    int r2 = vid / GY;
    int h_ = r2 % GZ;         // Hp = 8
    int d_ = r2 / GZ;         // Dp = 100

    float xg = -1.f + 2.f * (float)w_ / 99.f;
    float yg = -1.f + 2.f * (float)h_ / 7.f;
    float zg = -1.f + 2.f * (float)d_ / 99.f;

    float acc[OC];
#pragma unroll
    for (int o = 0; o < OC; ++o) acc[o] = b_T[o];

    for (int t = 0; t < NT; ++t) {
        const float* th = theta + (b * NT + t) * 12;
        float g0 = th[0] * xg + th[1] * yg + th[2] * zg + th[3];
        float g1 = th[4] * xg + th[5] * yg + th[6] * zg + th[7];
        float g2 = th[8] * xg + th[9] * yg + th[10] * zg + th[11];
        float ix = (g0 + 1.f) * 0.5f * 99.f;
        float iy = (g1 + 1.f) * 0.5f * 7.f;
        float iz = (g2 + 1.f) * 0.5f * 99.f;
        float x0 = floorf(ix), y0 = floorf(iy), z0 = floorf(iz);
        float wx1 = ix - x0, wy1 = iy - y0, wz1 = iz - z0;
        float wx0 = 1.f - wx1, wy0 = 1.f - wy1, wz0 = 1.f - wz1;

        float w8[8];
        int off8[8];
#pragma unroll
        for (int k = 0; k < 8; ++k) {
            float xf = x0 + (float)(k & 1);
            float yf = y0 + (float)((k >> 1) & 1);
            float zf = z0 + (float)(k >> 2);
            bool valid = (xf >= 0.f) & (xf <= 99.f) &
                         (yf >= 0.f) & (yf <= 7.f) &
                         (zf >= 0.f) & (zf <= 99.f);
            int xi = (int)fminf(fmaxf(xf, 0.f), 99.f);
            int yi = (int)fminf(fmaxf(yf, 0.f), 7.f);
            int zi = (int)fminf(fmaxf(zf, 0.f), 99.f);
            float w = ((k & 1) ? wx1 : wx0) * (((k >> 1) & 1) ? wy1 : wy0) *
                      ((k >> 2) ? wz1 : wz0);
            w8[k] = valid ? w : 0.f;
            off8[k] = (zi * GZ + yi) * GY + xi;  // voxel index in [vid] space
        }

        const float* hb = h + (size_t)(b * NT + t) * NVOX * OC;
        float sval[OC];
#pragma unroll
        for (int o2 = 0; o2 < OC; ++o2) sval[o2] = 0.f;
#pragma unroll
        for (int k = 0; k < 8; ++k) {
            float w = w8[k];
            const float4* cp =
                reinterpret_cast<const float4*>(hb + (size_t)off8[k] * OC);
#pragma unroll
            for (int q = 0; q < 10; ++q) {
                float4 v = cp[q];
                sval[4 * q + 0] = fmaf(w, v.x, sval[4 * q + 0]);
                sval[4 * q + 1] = fmaf(w, v.y, sval[4 * q + 1]);
                sval[4 * q + 2] = fmaf(w, v.z, sval[4 * q + 2]);
                sval[4 * q + 3] = fmaf(w, v.w, sval[4 * q + 3]);
            }
        }

        // acc[o] += W_T[o, t*40 + o2] * sval[o2]
#pragma unroll
        for (int o = 0; o < OC; ++o) {
            const float4* w4 =
                reinterpret_cast<const float4*>(W_T + o * (NT * OC) + t * OC);
#pragma unroll
            for (int q = 0; q < 10; ++q) {
                float4 w = w4[q];
                acc[o] = fmaf(w.x, sval[4 * q + 0], acc[o]);
                acc[o] = fmaf(w.y, sval[4 * q + 1], acc[o]);
                acc[o] = fmaf(w.z, sval[4 * q + 2], acc[o]);
                acc[o] = fmaf(w.w, sval[4 * q + 3], acc[o]);
            }
        }
    }

    float* op = out + (size_t)b * OC * NVOX + vid;
#pragma unroll
    for (int o = 0; o < OC; ++o) op[(size_t)o * NVOX] = fmaxf(acc[o], 0.f);
}

extern "C" void kernel_launch(void* const* d_in, const int* in_sizes, int n_in,
                              void* d_out, int out_size, void* d_ws, size_t ws_size,
                              hipStream_t stream) {
    const float* frustum = (const float*)d_in[0];
    const float* RT      = (const float*)d_in[1];
    const float* intrins = (const float*)d_in[2];
    const float* DoF     = (const float*)d_in[3];
    const float* W_N     = (const float*)d_in[4];
    const float* b_N     = (const float*)d_in[5];
    const float* W_T     = (const float*)d_in[6];
    const float* b_T     = (const float*)d_in[7];
    float* out = (float*)d_out;

    const size_t ft_f32 = FT_ELEMS * sizeof(float);           // ~170 MB
    const size_t ft_bf16 = FT_ELEMS * sizeof(unsigned short); // ~85 MB
    const size_t h_bytes = HSZ * sizeof(float);               // ~77 MB
    const size_t small = 4096;                                // P + theta

    char* base = (char*)d_ws;
    int mode;  // 0 = fp32 chlast, 1 = bf16 chlast, 2 = no transpose
    size_t ft_bytes;
    if (ws_size >= ft_f32 + h_bytes + small) { mode = 0; ft_bytes = ft_f32; }
    else if (ws_size >= ft_bf16 + h_bytes + small) { mode = 1; ft_bytes = ft_bf16; }
    else { mode = 2; ft_bytes = 0; }

    size_t ft_al = (ft_bytes + 255) & ~(size_t)255;
    void* ft_buf = base;
    float* h_buf = (float*)(base + ft_al);
    float* P_buf = (float*)(base + ft_al + ((h_bytes + 255) & ~(size_t)255));
    float* th_buf = P_buf + NB * NT * NCAM * 12;

    setup_kernel<<<1, 128, 0, stream>>>(RT, intrins, DoF, P_buf, th_buf);

    const int tr_blocks = (NB * NT * NCAM * FSZ) / 256;  // 10368
    const int n1_blocks = (NB * NT * NVOX) / 256;        // 1875
    const int n2_blocks = (NB * NVOX) / 256;             // 625

    if (mode == 0) {
        transpose_feat<float><<<tr_blocks, 256, 0, stream>>>(frustum, (float*)ft_buf);
        sample_mlp1<float, true><<<n1_blocks, 256, 0, stream>>>(
            frustum, (const float*)ft_buf, P_buf, W_N, b_N, h_buf);
    } else if (mode == 1) {
        transpose_feat<unsigned short><<<tr_blocks, 256, 0, stream>>>(
            frustum, (unsigned short*)ft_buf);
        sample_mlp1<unsigned short, true><<<n1_blocks, 256, 0, stream>>>(
            frustum, (const unsigned short*)ft_buf, P_buf, W_N, b_N, h_buf);
    } else {
        sample_mlp1<float, false><<<n1_blocks, 256, 0, stream>>>(
            frustum, (const float*)nullptr, P_buf, W_N, b_N, h_buf);
    }

    warp_mlp2<<<n2_blocks, 256, 0, stream>>>(h_buf, th_buf, W_T, b_T, out);
}